// Round 10
// baseline (11484.587 us; speedup 1.0000x reference)
//
#include <hip/hip_runtime.h>

typedef _Float16 half8 __attribute__((ext_vector_type(8)));
typedef float f32x4 __attribute__((ext_vector_type(4)));
typedef unsigned long long ull;

#define Bb 256
#define Tt 512
#define NF 64
#define H1u 256
#define H2u 128
#define NTHR 256
#define NBLK 64

#define NF1 10
#define NF2 12
#define NT1 4
#define NT2 2

// ws byte offsets (weight frag layout identical to rounds 4-9)
#define OFFB_WF1 0
#define SZB_WF1  (16*4*NF1*64*16)
#define OFFB_WF2 (OFFB_WF1+SZB_WF1)
#define SZB_WF2  (16*2*NF2*64*16)
#define OFFB_BF1 (OFFB_WF2+SZB_WF2)
#define SZB_BF1  (16*4*4*4*4)
#define OFFB_BF2 (OFFB_BF1+SZB_BF1)
#define SZB_BF2  (16*2*4*4*4)
#define OFFB_P1  (OFFB_BF2+SZB_BF2)   // [par2][grp16][b16][unit256] f32 (tagged)
#define SZB_P1   (2*16*16*256*4)      // 524288
#define OFFB_P2  (OFFB_P1+SZB_P1)     // [par2][grp16][b16][unit128] f32 (tagged)
#define SZB_P2   (2*16*16*128*4)      // 262144

__device__ __forceinline__ float sigf(float x) {
    return 1.0f / (1.0f + __expf(-x));
}
__device__ __forceinline__ float tanhfast(float x) {
    return 2.0f / (1.0f + __expf(-2.0f * x)) - 1.0f;
}
__device__ __forceinline__ unsigned tagf(float h, unsigned tag) {
    return (__float_as_uint(h) & 0xFFFFFF00u) | tag;
}
__device__ __forceinline__ half8 frag_from(const ull* q) {
    half8 r;
    #pragma unroll
    for (int j = 0; j < 4; ++j) {
        r[2 * j]     = (_Float16)__uint_as_float((unsigned)q[j]);
        r[2 * j + 1] = (_Float16)__uint_as_float((unsigned)(q[j] >> 32));
    }
    return r;
}

// ---------------- prep: weights -> MFMA A-fragments (fp16), proven rounds 4-9 ----------------
__global__ __launch_bounds__(256) void prep4(
    const float* __restrict__ Wih1, const float* __restrict__ Whh1,
    const float* __restrict__ bih1, const float* __restrict__ bhh1,
    const float* __restrict__ Wih2, const float* __restrict__ Whh2,
    const float* __restrict__ bih2, const float* __restrict__ bhh2,
    char* __restrict__ wsb)
{
    _Float16* wf1 = (_Float16*)(wsb + OFFB_WF1);
    _Float16* wf2 = (_Float16*)(wsb + OFFB_WF2);
    float*    bf1 = (float*)(wsb + OFFB_BF1);
    float*    bf2 = (float*)(wsb + OFFB_BF2);
    const int stride = gridDim.x * blockDim.x;
    const int i0 = blockIdx.x * blockDim.x + threadIdx.x;

    for (int idx = i0; idx < 16*4*NF1*64; idx += stride) {
        const int lane = idx & 63;
        int q = idx >> 6;
        const int f = q % NF1;  q /= NF1;
        const int tt = q & 3;
        const int w  = q >> 2;
        const int r = lane & 15;
        const int unit = w*16 + tt*4 + (r >> 2);
        const int gate = r & 3;
        const int grow = gate * H1u + unit;
        _Float16* dst = wf1 + (size_t)idx * 8;
        #pragma unroll
        for (int e = 0; e < 8; ++e) {
            const int k = f*32 + (lane >> 4)*8 + e;
            const float v = (k < NF) ? Wih1[grow*NF + k]
                                     : Whh1[grow*H1u + (k - NF)];
            dst[e] = (_Float16)v;
        }
    }
    for (int idx = i0; idx < 16*2*NF2*64; idx += stride) {
        const int lane = idx & 63;
        int q = idx >> 6;
        const int f = q % NF2;  q /= NF2;
        const int tt = q & 1;
        const int w  = q >> 1;
        const int r = lane & 15;
        const int unit = w*8 + tt*4 + (r >> 2);
        const int gate = r & 3;
        const int grow = gate * H2u + unit;
        _Float16* dst = wf2 + (size_t)idx * 8;
        #pragma unroll
        for (int e = 0; e < 8; ++e) {
            const int k = f*32 + (lane >> 4)*8 + e;
            const float v = (k < H1u) ? Wih2[grow*H1u + k]
                                      : Whh2[grow*H2u + (k - H1u)];
            dst[e] = (_Float16)v;
        }
    }
    for (int idx = i0; idx < 16*4*4*4; idx += stride) {
        const int reg = idx & 3, lg = (idx >> 2) & 3;
        const int tt = (idx >> 4) & 3, w = idx >> 6;
        const int unit = w*16 + tt*4 + lg;
        const int grow = reg * H1u + unit;
        bf1[idx] = bih1[grow] + bhh1[grow];
    }
    for (int idx = i0; idx < 16*2*4*4; idx += stride) {
        const int reg = idx & 3, lg = (idx >> 2) & 3;
        const int tt = (idx >> 4) & 1, w = idx >> 5;
        const int unit = w*8 + tt*4 + lg;
        const int grow = reg * H2u + unit;
        bf2[idx] = bih2[grow] + bhh2[grow];
    }
}

__device__ __forceinline__ void load_x_frags(half8* xf, const float* __restrict__ x,
                                             int b0, int b, int g, int t)
{
    #pragma unroll
    for (int f = 0; f < 2; ++f) {
        const float* xp = x + (((size_t)(b0 + b)) * Tt + t) * NF + f * 32 + g * 8;
        const float4 lo = *(const float4*)xp;
        const float4 hi = *(const float4*)(xp + 4);
        half8 v;
        v[0] = (_Float16)lo.x; v[1] = (_Float16)lo.y;
        v[2] = (_Float16)lo.z; v[3] = (_Float16)lo.w;
        v[4] = (_Float16)hi.x; v[5] = (_Float16)hi.y;
        v[6] = (_Float16)hi.z; v[7] = (_Float16)hi.w;
        xf[f] = v;
    }
}

// ---------------- persistent recurrence: 64 blocks = 16 groups x 4 slices,
// tagged-data exchange: no drains, no stamps, no LDS, no barriers ----------------
__global__ __launch_bounds__(NTHR, 1) void lstm_v10(
    const float* __restrict__ x, char* wsb, float* __restrict__ out)
{
    const int tid   = threadIdx.x;
    const int w     = tid >> 6;
    const int lane  = tid & 63;
    const int g     = lane >> 4;
    const int b     = lane & 15;
    const int grp   = blockIdx.x & 15;
    const int slice = blockIdx.x >> 4;
    const int W     = slice * 4 + w;
    const int b0    = grp * 16;

    const _Float16* wf1g = (const _Float16*)(wsb + OFFB_WF1);
    const _Float16* wf2g = (const _Float16*)(wsb + OFFB_WF2);
    const float*    bf1g = (const float*)(wsb + OFFB_BF1);
    const float*    bf2g = (const float*)(wsb + OFFB_BF2);
    unsigned*       p1s  = (unsigned*)(wsb + OFFB_P1);
    unsigned*       p2s  = (unsigned*)(wsb + OFFB_P2);
    const ull*      p1u  = (const ull*)(wsb + OFFB_P1);
    const ull*      p2u  = (const ull*)(wsb + OFFB_P2);

    // ---- one-time: weight fragments + biases -> registers ----
    half8 wA1[NT1][NF1];
    half8 wA2[NT2][NF2];
    #pragma unroll
    for (int tt = 0; tt < NT1; ++tt)
        #pragma unroll
        for (int f = 0; f < NF1; ++f)
            wA1[tt][f] = *(const half8*)(wf1g + ((size_t)(((W*4 + tt)*NF1 + f) * 64 + lane)) * 8);
    #pragma unroll
    for (int tt = 0; tt < NT2; ++tt)
        #pragma unroll
        for (int f = 0; f < NF2; ++f)
            wA2[tt][f] = *(const half8*)(wf2g + ((size_t)(((W*2 + tt)*NF2 + f) * 64 + lane)) * 8);

    f32x4 bias1[NT1], bias2[NT2];
    #pragma unroll
    for (int tt = 0; tt < NT1; ++tt)
        bias1[tt] = *(const f32x4*)(bf1g + ((W*4 + tt)*4 + g) * 4);
    #pragma unroll
    for (int tt = 0; tt < NT2; ++tt)
        bias2[tt] = *(const f32x4*)(bf2g + ((W*2 + tt)*4 + g) * 4);

    float c1s[NT1] = {0.f, 0.f, 0.f, 0.f};
    float c2s[NT2] = {0.f, 0.f};

    half8 hz = {};
    half8 hf[8]  = {hz, hz, hz, hz, hz, hz, hz, hz};
    half8 h2f[4] = {hz, hz, hz, hz};
    half8 xf[2];
    load_x_frags(xf, x, b0, b, g, 0);

    for (int t = 0; t <= Tt; ++t) {
        const unsigned tg = (unsigned)(t + 1) & 0xFFu;

        // ================ L1: compute h1(t), fire tagged stores ================
        if (t < Tt) {
            f32x4 acc[NT1] = {};
            #pragma unroll
            for (int tt = 0; tt < NT1; ++tt) {
                acc[tt] = __builtin_amdgcn_mfma_f32_16x16x32_f16(wA1[tt][0], xf[0], acc[tt], 0, 0, 0);
                acc[tt] = __builtin_amdgcn_mfma_f32_16x16x32_f16(wA1[tt][1], xf[1], acc[tt], 0, 0, 0);
            }
            #pragma unroll
            for (int f = 0; f < 8; ++f)
                #pragma unroll
                for (int tt = 0; tt < NT1; ++tt)
                    acc[tt] = __builtin_amdgcn_mfma_f32_16x16x32_f16(wA1[tt][2 + f], hf[f], acc[tt], 0, 0, 0);
            const size_t s1 = (size_t)((t & 1) * 16 + grp) * 4096 + (size_t)b * 256;
            #pragma unroll
            for (int tt = 0; tt < NT1; ++tt) {
                const float iv = sigf(acc[tt][0] + bias1[tt][0]);
                const float fv = sigf(acc[tt][1] + bias1[tt][1]);
                const float gv = tanhfast(acc[tt][2] + bias1[tt][2]);
                const float ov = sigf(acc[tt][3] + bias1[tt][3]);
                const float c = fmaf(fv, c1s[tt], iv * gv);
                c1s[tt] = c;
                const float h = ov * tanhfast(c);
                const int u1 = W * 16 + tt * 4 + g;
                __hip_atomic_store(p1s + s1 + u1, tagf(h, tg),
                                   __ATOMIC_RELAXED, __HIP_MEMORY_SCOPE_AGENT);
            }
        }
        // ================ L2: compute h2(t-1), fire tagged + out stores ================
        if (t >= 1) {
            f32x4 acc[NT2] = {};
            #pragma unroll
            for (int f = 0; f < 8; ++f)
                #pragma unroll
                for (int tt = 0; tt < NT2; ++tt)
                    acc[tt] = __builtin_amdgcn_mfma_f32_16x16x32_f16(wA2[tt][f], hf[f], acc[tt], 0, 0, 0);
            #pragma unroll
            for (int f = 0; f < 4; ++f)
                #pragma unroll
                for (int tt = 0; tt < NT2; ++tt)
                    acc[tt] = __builtin_amdgcn_mfma_f32_16x16x32_f16(wA2[tt][8 + f], h2f[f], acc[tt], 0, 0, 0);
            const size_t s2 = (size_t)(((t + 1) & 1) * 16 + grp) * 2048 + (size_t)b * 128;
            const int s_ = t - 1;
            #pragma unroll
            for (int tt = 0; tt < NT2; ++tt) {
                const float iv = sigf(acc[tt][0] + bias2[tt][0]);
                const float fv = sigf(acc[tt][1] + bias2[tt][1]);
                const float gv = tanhfast(acc[tt][2] + bias2[tt][2]);
                const float ov = sigf(acc[tt][3] + bias2[tt][3]);
                const float c = fmaf(fv, c2s[tt], iv * gv);
                c2s[tt] = c;
                const float h = ov * tanhfast(c);
                const int u2 = W * 8 + tt * 4 + g;
                if (t < Tt)
                    __hip_atomic_store(p2s + s2 + u2, tagf(h, tg),
                                       __ATOMIC_RELAXED, __HIP_MEMORY_SCOPE_AGENT);
                out[((size_t)(b0 + b) * Tt + s_) * H2u + u2] = h;
                if (s_ == Tt - 1)
                    out[(size_t)Bb * Tt * H2u + (size_t)(b0 + b) * H2u + u2] = h;
            }
        } else {
            // t == 0: publish tagged zero-h2 so end-of-step-0 consumers make progress
            const size_t s2 = (size_t)(1 * 16 + grp) * 2048 + (size_t)b * 128;
            #pragma unroll
            for (int tt = 0; tt < NT2; ++tt) {
                const int u2 = W * 8 + tt * 4 + g;
                __hip_atomic_store(p2s + s2 + u2, tagf(0.f, 1u),
                                   __ATOMIC_RELAXED, __HIP_MEMORY_SCOPE_AGENT);
            }
        }

        // ================ x prefetch (overlaps store flight) ================
        if (t + 1 < Tt) load_x_frags(xf, x, b0, b, g, t + 1);

        // ================ tagged retry-load: poll+data in one round trip ================
        if (t < Tt) {
            const ull tg2 = (ull)tg * 0x100000001ull;
            const size_t ub1 = (size_t)((t & 1) * 16 + grp) * 2048 + (size_t)b * 128 + 4 * g;
            const size_t ub2 = (size_t)(((t + 1) & 1) * 16 + grp) * 1024 + (size_t)b * 64 + 4 * g;
            ull q[48];
            for (;;) {
                asm volatile("" ::: "memory");   // force re-load each iter; pin stores above
                #pragma unroll
                for (int f = 0; f < 8; ++f)
                    #pragma unroll
                    for (int j = 0; j < 4; ++j)
                        q[f * 4 + j] = __hip_atomic_load(p1u + ub1 + 16 * f + j,
                                           __ATOMIC_RELAXED, __HIP_MEMORY_SCOPE_AGENT);
                #pragma unroll
                for (int f = 0; f < 4; ++f)
                    #pragma unroll
                    for (int j = 0; j < 4; ++j)
                        q[32 + f * 4 + j] = __hip_atomic_load(p2u + ub2 + 16 * f + j,
                                                __ATOMIC_RELAXED, __HIP_MEMORY_SCOPE_AGENT);
                unsigned bad = 0u;
                #pragma unroll
                for (int i = 0; i < 48; ++i) {
                    const ull d = q[i] ^ tg2;
                    bad |= ((unsigned)d | (unsigned)(d >> 32)) & 0xFFu;
                }
                if (__all((int)(bad == 0u))) break;
                __builtin_amdgcn_s_sleep(1);
            }
            #pragma unroll
            for (int f = 0; f < 8; ++f) hf[f] = frag_from(&q[f * 4]);
            #pragma unroll
            for (int f = 0; f < 4; ++f) h2f[f] = frag_from(&q[32 + f * 4]);
        }
    }
}

extern "C" void kernel_launch(void* const* d_in, const int* in_sizes, int n_in,
                              void* d_out, int out_size, void* d_ws, size_t ws_size,
                              hipStream_t stream) {
    const float* x    = (const float*)d_in[0];
    const float* Wih1 = (const float*)d_in[1];
    const float* Whh1 = (const float*)d_in[2];
    const float* bih1 = (const float*)d_in[3];
    const float* bhh1 = (const float*)d_in[4];
    const float* Wih2 = (const float*)d_in[5];
    const float* Whh2 = (const float*)d_in[6];
    const float* bih2 = (const float*)d_in[7];
    const float* bhh2 = (const float*)d_in[8];
    char*  wsb = (char*)d_ws;
    float* out = (float*)d_out;

    prep4<<<256, 256, 0, stream>>>(Wih1, Whh1, bih1, bhh1,
                                   Wih2, Whh2, bih2, bhh2, wsb);
    // hygiene zero of panels (tags make this optional for correctness)
    hipMemsetAsync((void*)(wsb + OFFB_P1), 0, SZB_P1 + SZB_P2, stream);
    lstm_v10<<<NBLK, NTHR, 0, stream>>>(x, wsb, out);
}

// Round 11
// 3281.464 us; speedup vs baseline: 3.4998x; 3.4998x over previous
//
#include <hip/hip_runtime.h>

typedef _Float16 half8 __attribute__((ext_vector_type(8)));
typedef float f32x4 __attribute__((ext_vector_type(4)));
typedef unsigned long long ull;

typedef ull      __attribute__((may_alias)) ull_a;
typedef unsigned __attribute__((may_alias)) u32_a;
typedef float4   __attribute__((may_alias)) float4_a;

#define LGKM_BAR() asm volatile("s_waitcnt lgkmcnt(0)" ::: "memory")
#define VM0_BAR()  do { asm volatile("s_waitcnt vmcnt(0)" ::: "memory"); \
                        __builtin_amdgcn_sched_barrier(0); } while (0)

#define Bb 256
#define Tt 512
#define NF 64
#define H1u 256
#define H2u 128
#define NTHR 256
#define NBLK 64

#define NF1 10
#define NF2 12
#define NT1 4
#define NT2 2

// ws byte offsets (weight frag layout identical to rounds 4-10)
#define OFFB_WF1 0
#define SZB_WF1  (16*4*NF1*64*16)
#define OFFB_WF2 (OFFB_WF1+SZB_WF1)
#define SZB_WF2  (16*2*NF2*64*16)
#define OFFB_BF1 (OFFB_WF2+SZB_WF2)
#define SZB_BF1  (16*4*4*4*4)
#define OFFB_BF2 (OFFB_BF1+SZB_BF1)
#define SZB_BF2  (16*2*4*4*4)
#define OFFB_P1  (OFFB_BF2+SZB_BF2)   // [par2][grp16][b16][u256] f32 tagged, 16KB slab
#define SZB_P1   (2*16*16384)
#define OFFB_P2  (OFFB_P1+SZB_P1)     // [par2][grp16][b16][u128] f32 tagged, 8KB slab
#define SZB_P2   (2*16*8192)

__device__ __forceinline__ float sigf(float x) {
    return 1.0f / (1.0f + __expf(-x));
}
__device__ __forceinline__ float tanhfast(float x) {
    return 2.0f / (1.0f + __expf(-2.0f * x)) - 1.0f;
}
__device__ __forceinline__ float tagf(float h, unsigned tag) {
    return __uint_as_float((__float_as_uint(h) & 0xFFFFFF00u) | tag);
}
__device__ __forceinline__ unsigned chkw(float x, unsigned tg) {
    return (__float_as_uint(x) ^ tg) & 255u;
}
__device__ __forceinline__ unsigned chk4(float4 v, unsigned tg) {
    return chkw(v.x, tg) | chkw(v.y, tg) | chkw(v.z, tg) | chkw(v.w, tg);
}
__device__ __forceinline__ half8 mk8(float4 lo, float4 hi) {
    half8 r;
    r[0] = (_Float16)lo.x; r[1] = (_Float16)lo.y;
    r[2] = (_Float16)lo.z; r[3] = (_Float16)lo.w;
    r[4] = (_Float16)hi.x; r[5] = (_Float16)hi.y;
    r[6] = (_Float16)hi.z; r[7] = (_Float16)hi.w;
    return r;
}
__device__ __forceinline__ unsigned chku(ull a, unsigned tg) {
    return ((((unsigned)a) ^ tg) | (((unsigned)(a >> 32)) ^ tg)) & 255u;
}
__device__ __forceinline__ half8 mk8u(ull a0, ull a1, ull a2, ull a3) {
    half8 r;
    r[0] = (_Float16)__uint_as_float((unsigned)a0);
    r[1] = (_Float16)__uint_as_float((unsigned)(a0 >> 32));
    r[2] = (_Float16)__uint_as_float((unsigned)a1);
    r[3] = (_Float16)__uint_as_float((unsigned)(a1 >> 32));
    r[4] = (_Float16)__uint_as_float((unsigned)a2);
    r[5] = (_Float16)__uint_as_float((unsigned)(a2 >> 32));
    r[6] = (_Float16)__uint_as_float((unsigned)a3);
    r[7] = (_Float16)__uint_as_float((unsigned)(a3 >> 32));
    return r;
}
// device-coherent global->LDS: lands lane i's 16B at ldsbase + i*16
__device__ __forceinline__ void gll16(const void* g, void* l) {
    __builtin_amdgcn_global_load_lds(
        (const __attribute__((address_space(1))) void*)g,
        (__attribute__((address_space(3))) void*)l, 16, 0, 17 /*SC0|SC1*/);
}

// ---------------- prep: weights -> MFMA A-fragments (fp16), proven rounds 4-10 ----------------
__global__ __launch_bounds__(256) void prep4(
    const float* __restrict__ Wih1, const float* __restrict__ Whh1,
    const float* __restrict__ bih1, const float* __restrict__ bhh1,
    const float* __restrict__ Wih2, const float* __restrict__ Whh2,
    const float* __restrict__ bih2, const float* __restrict__ bhh2,
    char* __restrict__ wsb)
{
    _Float16* wf1 = (_Float16*)(wsb + OFFB_WF1);
    _Float16* wf2 = (_Float16*)(wsb + OFFB_WF2);
    float*    bf1 = (float*)(wsb + OFFB_BF1);
    float*    bf2 = (float*)(wsb + OFFB_BF2);
    const int stride = gridDim.x * blockDim.x;
    const int i0 = blockIdx.x * blockDim.x + threadIdx.x;

    for (int idx = i0; idx < 16*4*NF1*64; idx += stride) {
        const int lane = idx & 63;
        int q = idx >> 6;
        const int f = q % NF1;  q /= NF1;
        const int tt = q & 3;
        const int w  = q >> 2;
        const int r = lane & 15;
        const int unit = w*16 + tt*4 + (r >> 2);
        const int gate = r & 3;
        const int grow = gate * H1u + unit;
        _Float16* dst = wf1 + (size_t)idx * 8;
        #pragma unroll
        for (int e = 0; e < 8; ++e) {
            const int k = f*32 + (lane >> 4)*8 + e;
            const float v = (k < NF) ? Wih1[grow*NF + k]
                                     : Whh1[grow*H1u + (k - NF)];
            dst[e] = (_Float16)v;
        }
    }
    for (int idx = i0; idx < 16*2*NF2*64; idx += stride) {
        const int lane = idx & 63;
        int q = idx >> 6;
        const int f = q % NF2;  q /= NF2;
        const int tt = q & 1;
        const int w  = q >> 1;
        const int r = lane & 15;
        const int unit = w*8 + tt*4 + (r >> 2);
        const int gate = r & 3;
        const int grow = gate * H2u + unit;
        _Float16* dst = wf2 + (size_t)idx * 8;
        #pragma unroll
        for (int e = 0; e < 8; ++e) {
            const int k = f*32 + (lane >> 4)*8 + e;
            const float v = (k < H1u) ? Wih2[grow*H1u + k]
                                      : Whh2[grow*H2u + (k - H1u)];
            dst[e] = (_Float16)v;
        }
    }
    for (int idx = i0; idx < 16*4*4*4; idx += stride) {
        const int reg = idx & 3, lg = (idx >> 2) & 3;
        const int tt = (idx >> 4) & 3, w = idx >> 6;
        const int unit = w*16 + tt*4 + lg;
        const int grow = reg * H1u + unit;
        bf1[idx] = bih1[grow] + bhh1[grow];
    }
    for (int idx = i0; idx < 16*2*4*4; idx += stride) {
        const int reg = idx & 3, lg = (idx >> 2) & 3;
        const int tt = (idx >> 4) & 1, w = idx >> 5;
        const int unit = w*8 + tt*4 + lg;
        const int grow = reg * H2u + unit;
        bf2[idx] = bih2[grow] + bhh2[grow];
    }
}

__device__ __forceinline__ void load_x_frags(half8* xf, const float* __restrict__ x,
                                             int b0, int b, int g, int t)
{
    #pragma unroll
    for (int f = 0; f < 2; ++f) {
        const float* xp = x + (((size_t)(b0 + b)) * Tt + t) * NF + f * 32 + g * 8;
        const float4 lo = *(const float4*)xp;
        const float4 hi = *(const float4*)(xp + 4);
        half8 v;
        v[0] = (_Float16)lo.x; v[1] = (_Float16)lo.y;
        v[2] = (_Float16)lo.z; v[3] = (_Float16)lo.w;
        v[4] = (_Float16)hi.x; v[5] = (_Float16)hi.y;
        v[6] = (_Float16)hi.z; v[7] = (_Float16)hi.w;
        xf[f] = v;
    }
}

// ---------------- persistent recurrence: 64 blocks = 16 groups x 4 slices,
// tagged f32 exchange, LDS-landed consumer loads, atomic fallback ----------------
__global__ __launch_bounds__(NTHR, 1) void lstm_v11(
    const float* __restrict__ x, char* wsb, float* __restrict__ out)
{
    __shared__ __align__(16) char  ldsC[4][24576];   // 96KB landing (24 x 1KB per wave)
    __shared__ __align__(16) float s1t[4][256];      // [w][b*16+u]  tagged f32
    __shared__ __align__(16) float s2t[4][128];      // [w][b*8+u]   tagged f32
    __shared__ __align__(16) float l_ot[4][128];     // [w][b*8+u]   out f32

    const int tid   = threadIdx.x;
    const int w     = tid >> 6;
    const int lane  = tid & 63;
    const int g     = lane >> 4;
    const int b     = lane & 15;
    const int grp   = blockIdx.x & 15;
    const int slice = blockIdx.x >> 4;
    const int W     = slice * 4 + w;
    const int b0    = grp * 16;

    const _Float16* wf1g = (const _Float16*)(wsb + OFFB_WF1);
    const _Float16* wf2g = (const _Float16*)(wsb + OFFB_WF2);
    const float*    bf1g = (const float*)(wsb + OFFB_BF1);
    const float*    bf2g = (const float*)(wsb + OFFB_BF2);
    char*           p1b  = wsb + OFFB_P1;
    char*           p2b  = wsb + OFFB_P2;
    ull*            p1u  = (ull*)p1b;
    ull*            p2u  = (ull*)p2b;

    // ---- one-time: weight fragments + biases -> registers ----
    half8 wA1[NT1][NF1];
    half8 wA2[NT2][NF2];
    #pragma unroll
    for (int tt = 0; tt < NT1; ++tt)
        #pragma unroll
        for (int f = 0; f < NF1; ++f)
            wA1[tt][f] = *(const half8*)(wf1g + ((size_t)(((W*4 + tt)*NF1 + f) * 64 + lane)) * 8);
    #pragma unroll
    for (int tt = 0; tt < NT2; ++tt)
        #pragma unroll
        for (int f = 0; f < NF2; ++f)
            wA2[tt][f] = *(const half8*)(wf2g + ((size_t)(((W*2 + tt)*NF2 + f) * 64 + lane)) * 8);

    f32x4 bias1[NT1], bias2[NT2];
    #pragma unroll
    for (int tt = 0; tt < NT1; ++tt)
        bias1[tt] = *(const f32x4*)(bf1g + ((W*4 + tt)*4 + g) * 4);
    #pragma unroll
    for (int tt = 0; tt < NT2; ++tt)
        bias2[tt] = *(const f32x4*)(bf2g + ((W*2 + tt)*4 + g) * 4);

    float c1s[NT1] = {0.f, 0.f, 0.f, 0.f};
    float c2s[NT2] = {0.f, 0.f};

    half8 hz = {};
    half8 hf[8]  = {hz, hz, hz, hz, hz, hz, hz, hz};
    half8 h2f[4] = {hz, hz, hz, hz};
    half8 xf[2];
    load_x_frags(xf, x, b0, b, g, 0);

    bool slow = false;

    for (int t = 0; t <= Tt; ++t) {
        const unsigned tg = (unsigned)(t + 1) & 255u;

        // ================ L1: compute h1(t), stage tagged into LDS ================
        if (t < Tt) {
            f32x4 acc[NT1] = {};
            #pragma unroll
            for (int tt = 0; tt < NT1; ++tt) {
                acc[tt] = __builtin_amdgcn_mfma_f32_16x16x32_f16(wA1[tt][0], xf[0], acc[tt], 0, 0, 0);
                acc[tt] = __builtin_amdgcn_mfma_f32_16x16x32_f16(wA1[tt][1], xf[1], acc[tt], 0, 0, 0);
            }
            #pragma unroll
            for (int f = 0; f < 8; ++f)
                #pragma unroll
                for (int tt = 0; tt < NT1; ++tt)
                    acc[tt] = __builtin_amdgcn_mfma_f32_16x16x32_f16(wA1[tt][2 + f], hf[f], acc[tt], 0, 0, 0);
            #pragma unroll
            for (int tt = 0; tt < NT1; ++tt) {
                const float iv = sigf(acc[tt][0] + bias1[tt][0]);
                const float fv = sigf(acc[tt][1] + bias1[tt][1]);
                const float gv = tanhfast(acc[tt][2] + bias1[tt][2]);
                const float ov = sigf(acc[tt][3] + bias1[tt][3]);
                const float c = fmaf(fv, c1s[tt], iv * gv);
                c1s[tt] = c;
                const float h = ov * tanhfast(c);
                s1t[w][b * 16 + tt * 4 + g] = tagf(h, tg);
            }
        }
        // ================ L2: compute h2(t-1), stage tagged + out ================
        if (t >= 1) {
            f32x4 acc[NT2] = {};
            #pragma unroll
            for (int f = 0; f < 8; ++f)
                #pragma unroll
                for (int tt = 0; tt < NT2; ++tt)
                    acc[tt] = __builtin_amdgcn_mfma_f32_16x16x32_f16(wA2[tt][f], hf[f], acc[tt], 0, 0, 0);
            #pragma unroll
            for (int f = 0; f < 4; ++f)
                #pragma unroll
                for (int tt = 0; tt < NT2; ++tt)
                    acc[tt] = __builtin_amdgcn_mfma_f32_16x16x32_f16(wA2[tt][8 + f], h2f[f], acc[tt], 0, 0, 0);
            #pragma unroll
            for (int tt = 0; tt < NT2; ++tt) {
                const float iv = sigf(acc[tt][0] + bias2[tt][0]);
                const float fv = sigf(acc[tt][1] + bias2[tt][1]);
                const float gv = tanhfast(acc[tt][2] + bias2[tt][2]);
                const float ov = sigf(acc[tt][3] + bias2[tt][3]);
                const float c = fmaf(fv, c2s[tt], iv * gv);
                c2s[tt] = c;
                const float h = ov * tanhfast(c);
                if (t < Tt) s2t[w][b * 8 + tt * 4 + g] = tagf(h, tg);
                l_ot[w][b * 8 + tt * 4 + g] = h;
            }
        }
        LGKM_BAR();   // pin LDS stage writes before type-punned readbacks

        // ================ producer: coalesced tagged stores (fire-and-forget) ================
        if (t < Tt) {
            const int bq = lane >> 2, jq = lane & 3;
            {
                const ull v0 = ((const ull_a*)&s1t[w][0])[lane * 2 + 0];
                const ull v1 = ((const ull_a*)&s1t[w][0])[lane * 2 + 1];
                const size_t d1 = (size_t)((t & 1) * 16 + grp) * 2048 + bq * 128 + W * 8 + jq * 2;
                __hip_atomic_store(p1u + d1,     v0, __ATOMIC_RELAXED, __HIP_MEMORY_SCOPE_AGENT);
                __hip_atomic_store(p1u + d1 + 1, v1, __ATOMIC_RELAXED, __HIP_MEMORY_SCOPE_AGENT);
            }
            {
                ull v2;
                if (t >= 1) v2 = ((const ull_a*)&s2t[w][0])[lane];
                else {
                    const unsigned z = __float_as_uint(tagf(0.f, tg));
                    v2 = (ull)z | ((ull)z << 32);
                }
                const size_t d2 = (size_t)(((t + 1) & 1) * 16 + grp) * 1024 + bq * 64 + W * 4 + jq;
                __hip_atomic_store(p2u + d2, v2, __ATOMIC_RELAXED, __HIP_MEMORY_SCOPE_AGENT);
            }
        }
        // ================ out writes + x prefetch (overlap store propagation) ================
        if (t >= 1 && lane < 32) {
            const int s_ = t - 1;
            const int bb = lane >> 1, q = lane & 1;
            const float4 ov = *(const float4_a*)(&l_ot[w][0] + bb * 8 + q * 4);
            *(float4*)&out[((size_t)(b0 + bb) * Tt + s_) * H2u + W * 8 + q * 4] = ov;
            if (s_ == Tt - 1)
                *(float4*)&out[(size_t)Bb * Tt * H2u + (size_t)(b0 + bb) * H2u + W * 8 + q * 4] = ov;
        }
        if (t + 1 < Tt) load_x_frags(xf, x, b0, b, g, t + 1);

        // ================ consumer: tagged LDS-landed loads (1 RTT), atomic fallback ================
        if (t < Tt) {
            const char* gp1 = p1b + (size_t)((t & 1) * 16 + grp) * 16384 + (size_t)b * 1024 + g * 32;
            const char* gp2 = p2b + (size_t)(((t + 1) & 1) * 16 + grp) * 8192 + (size_t)b * 512 + g * 32;
            char* cw = &ldsC[w][0];
            if (!slow) {
                int att = 0;
                bool ok = false;
                for (;;) {
                    #pragma unroll
                    for (int f = 0; f < 8; ++f) {
                        gll16(gp1 + f * 128,      cw + (f * 2 + 0) * 1024);
                        gll16(gp1 + f * 128 + 16, cw + (f * 2 + 1) * 1024);
                    }
                    #pragma unroll
                    for (int f = 0; f < 4; ++f) {
                        gll16(gp2 + f * 128,      cw + (16 + f * 2) * 1024);
                        gll16(gp2 + f * 128 + 16, cw + (17 + f * 2) * 1024);
                    }
                    VM0_BAR();
                    unsigned bad = 0;
                    #pragma unroll
                    for (int f = 0; f < 8; ++f) {
                        const float4 lo = *(const float4_a*)(cw + (f * 2 + 0) * 1024 + lane * 16);
                        const float4 hi = *(const float4_a*)(cw + (f * 2 + 1) * 1024 + lane * 16);
                        bad |= chk4(lo, tg) | chk4(hi, tg);
                        hf[f] = mk8(lo, hi);
                    }
                    #pragma unroll
                    for (int f = 0; f < 4; ++f) {
                        const float4 lo = *(const float4_a*)(cw + (16 + f * 2) * 1024 + lane * 16);
                        const float4 hi = *(const float4_a*)(cw + (17 + f * 2) * 1024 + lane * 16);
                        bad |= chk4(lo, tg) | chk4(hi, tg);
                        h2f[f] = mk8(lo, hi);
                    }
                    if (__all((int)(bad == 0u))) { ok = true; break; }
                    if (++att > 24) break;
                    __builtin_amdgcn_s_sleep(1);
                }
                if (!ok) slow = true;   // coherence assumption failed -> proven path
            }
            if (slow) {
                const ull* q1 = p1u + (size_t)((t & 1) * 16 + grp) * 2048 + (size_t)b * 128 + g * 4;
                const ull* q2 = p2u + (size_t)(((t + 1) & 1) * 16 + grp) * 1024 + (size_t)b * 64 + g * 4;
                for (;;) {
                    unsigned bad = 0;
                    #pragma unroll
                    for (int f = 0; f < 8; ++f) {
                        const ull a0 = __hip_atomic_load(q1 + f * 16 + 0, __ATOMIC_RELAXED, __HIP_MEMORY_SCOPE_AGENT);
                        const ull a1 = __hip_atomic_load(q1 + f * 16 + 1, __ATOMIC_RELAXED, __HIP_MEMORY_SCOPE_AGENT);
                        const ull a2 = __hip_atomic_load(q1 + f * 16 + 2, __ATOMIC_RELAXED, __HIP_MEMORY_SCOPE_AGENT);
                        const ull a3 = __hip_atomic_load(q1 + f * 16 + 3, __ATOMIC_RELAXED, __HIP_MEMORY_SCOPE_AGENT);
                        bad |= chku(a0, tg) | chku(a1, tg) | chku(a2, tg) | chku(a3, tg);
                        hf[f] = mk8u(a0, a1, a2, a3);
                    }
                    #pragma unroll
                    for (int f = 0; f < 4; ++f) {
                        const ull a0 = __hip_atomic_load(q2 + f * 16 + 0, __ATOMIC_RELAXED, __HIP_MEMORY_SCOPE_AGENT);
                        const ull a1 = __hip_atomic_load(q2 + f * 16 + 1, __ATOMIC_RELAXED, __HIP_MEMORY_SCOPE_AGENT);
                        const ull a2 = __hip_atomic_load(q2 + f * 16 + 2, __ATOMIC_RELAXED, __HIP_MEMORY_SCOPE_AGENT);
                        const ull a3 = __hip_atomic_load(q2 + f * 16 + 3, __ATOMIC_RELAXED, __HIP_MEMORY_SCOPE_AGENT);
                        bad |= chku(a0, tg) | chku(a1, tg) | chku(a2, tg) | chku(a3, tg);
                        h2f[f] = mk8u(a0, a1, a2, a3);
                    }
                    if (__all((int)(bad == 0u))) break;
                    __builtin_amdgcn_s_sleep(1);
                    asm volatile("" ::: "memory");
                }
            }
        }
    }
}

extern "C" void kernel_launch(void* const* d_in, const int* in_sizes, int n_in,
                              void* d_out, int out_size, void* d_ws, size_t ws_size,
                              hipStream_t stream) {
    const float* x    = (const float*)d_in[0];
    const float* Wih1 = (const float*)d_in[1];
    const float* Whh1 = (const float*)d_in[2];
    const float* bih1 = (const float*)d_in[3];
    const float* bhh1 = (const float*)d_in[4];
    const float* Wih2 = (const float*)d_in[5];
    const float* Whh2 = (const float*)d_in[6];
    const float* bih2 = (const float*)d_in[7];
    const float* bhh2 = (const float*)d_in[8];
    char*  wsb = (char*)d_ws;
    float* out = (float*)d_out;

    prep4<<<256, 256, 0, stream>>>(Wih1, Whh1, bih1, bhh1,
                                   Wih2, Whh2, bih2, bhh2, wsb);
    // zero panels every launch (tags -> all stale at t=0; deterministic)
    hipMemsetAsync((void*)(wsb + OFFB_P1), 0, SZB_P1 + SZB_P2, stream);
    lstm_v11<<<NBLK, NTHR, 0, stream>>>(x, wsb, out);
}

// Round 12
// 2303.968 us; speedup vs baseline: 4.9847x; 1.4243x over previous
//
#include <hip/hip_runtime.h>

typedef _Float16 half8 __attribute__((ext_vector_type(8)));
typedef float f32x4 __attribute__((ext_vector_type(4)));
typedef int i32x4 __attribute__((ext_vector_type(4)));
typedef unsigned long long ull;

typedef ull      __attribute__((may_alias)) ull_a;
typedef float4   __attribute__((may_alias)) float4_a;

#define LGKM_BAR() asm volatile("s_waitcnt lgkmcnt(0)" ::: "memory")

#define Bb 256
#define Tt 512
#define NF 64
#define H1u 256
#define H2u 128
#define NTHR 256
#define NLAUNCH 512

#define NF1 10
#define NF2 12
#define NT1 4
#define NT2 2

// ws byte offsets (weight frag layout identical to rounds 4-11)
#define OFFB_WF1 0
#define SZB_WF1  (16*4*NF1*64*16)
#define OFFB_WF2 (OFFB_WF1+SZB_WF1)
#define SZB_WF2  (16*2*NF2*64*16)
#define OFFB_BF1 (OFFB_WF2+SZB_WF2)
#define SZB_BF1  (16*4*4*4*4)
#define OFFB_BF2 (OFFB_BF1+SZB_BF1)
#define SZB_BF2  (16*2*4*4*4)
#define OFFB_P1  (OFFB_BF2+SZB_BF2)   // [par2][grp16][W16][b16][uloc16] f32 tagged
#define SZB_P1   (2*16*16384)
#define OFFB_P2  (OFFB_P1+SZB_P1)     // [par2][grp16][W16][b16][uloc8] f32 tagged
#define SZB_P2   (2*16*8192)
#define OFFB_CLM (OFFB_P2+SZB_P2)     // [xcd8][16 u32] claim counters
#define SZB_CLM  (8*64)

__device__ __forceinline__ float sigf(float x) {
    return 1.0f / (1.0f + __expf(-x));
}
__device__ __forceinline__ float tanhfast(float x) {
    return 2.0f / (1.0f + __expf(-2.0f * x)) - 1.0f;
}
__device__ __forceinline__ float tagf(float h, unsigned tag) {
    return __uint_as_float((__float_as_uint(h) & 0xFFFFFF00u) | tag);
}
__device__ __forceinline__ unsigned chki(i32x4 v, unsigned tg) {
    return (((unsigned)v[0] ^ tg) | ((unsigned)v[1] ^ tg) |
            ((unsigned)v[2] ^ tg) | ((unsigned)v[3] ^ tg)) & 255u;
}
__device__ __forceinline__ half8 mk8i(i32x4 lo, i32x4 hi) {
    half8 r;
    r[0] = (_Float16)__int_as_float(lo[0]); r[1] = (_Float16)__int_as_float(lo[1]);
    r[2] = (_Float16)__int_as_float(lo[2]); r[3] = (_Float16)__int_as_float(lo[3]);
    r[4] = (_Float16)__int_as_float(hi[0]); r[5] = (_Float16)__int_as_float(hi[1]);
    r[6] = (_Float16)__int_as_float(hi[2]); r[7] = (_Float16)__int_as_float(hi[3]);
    return r;
}
__device__ __forceinline__ unsigned chku(ull a, unsigned tg) {
    return ((((unsigned)a) ^ tg) | (((unsigned)(a >> 32)) ^ tg)) & 255u;
}
__device__ __forceinline__ half8 mk8u(ull a0, ull a1, ull a2, ull a3) {
    half8 r;
    r[0] = (_Float16)__uint_as_float((unsigned)a0);
    r[1] = (_Float16)__uint_as_float((unsigned)(a0 >> 32));
    r[2] = (_Float16)__uint_as_float((unsigned)a1);
    r[3] = (_Float16)__uint_as_float((unsigned)(a1 >> 32));
    r[4] = (_Float16)__uint_as_float((unsigned)a2);
    r[5] = (_Float16)__uint_as_float((unsigned)(a2 >> 32));
    r[6] = (_Float16)__uint_as_float((unsigned)a3);
    r[7] = (_Float16)__uint_as_float((unsigned)(a3 >> 32));
    return r;
}
__device__ __forceinline__ int xcc_id() {
    int v;
    asm volatile("s_getreg_b32 %0, hwreg(HW_REG_XCC_ID)" : "=s"(v));
    return v & 7;
}
// 8x dwordx4 sc0 (L1-bypass) loads off two bases, offsets {0,16,2048,2064}
#define LOAD8_SC0(pA, pB, o0,o1,o2,o3,o4,o5,o6,o7)                         \
    asm volatile(                                                           \
        "global_load_dwordx4 %[v0], %[a], off sc0\n\t"                      \
        "global_load_dwordx4 %[v1], %[a], off offset:16 sc0\n\t"            \
        "global_load_dwordx4 %[v2], %[a], off offset:2048 sc0\n\t"          \
        "global_load_dwordx4 %[v3], %[a], off offset:2064 sc0\n\t"          \
        "global_load_dwordx4 %[v4], %[b], off sc0\n\t"                      \
        "global_load_dwordx4 %[v5], %[b], off offset:16 sc0\n\t"            \
        "global_load_dwordx4 %[v6], %[b], off offset:2048 sc0\n\t"          \
        "global_load_dwordx4 %[v7], %[b], off offset:2064 sc0\n\t"          \
        "s_waitcnt vmcnt(0)"                                                \
        : [v0]"=&v"(o0), [v1]"=&v"(o1), [v2]"=&v"(o2), [v3]"=&v"(o3),       \
          [v4]"=&v"(o4), [v5]"=&v"(o5), [v6]"=&v"(o6), [v7]"=&v"(o7)        \
        : [a]"v"(pA), [b]"v"(pB)                                            \
        : "memory");                                                        \
    __builtin_amdgcn_sched_barrier(0)

// ---------------- prep: weights -> MFMA A-fragments (fp16), proven rounds 4-11 ----------------
__global__ __launch_bounds__(256) void prep4(
    const float* __restrict__ Wih1, const float* __restrict__ Whh1,
    const float* __restrict__ bih1, const float* __restrict__ bhh1,
    const float* __restrict__ Wih2, const float* __restrict__ Whh2,
    const float* __restrict__ bih2, const float* __restrict__ bhh2,
    char* __restrict__ wsb)
{
    _Float16* wf1 = (_Float16*)(wsb + OFFB_WF1);
    _Float16* wf2 = (_Float16*)(wsb + OFFB_WF2);
    float*    bf1 = (float*)(wsb + OFFB_BF1);
    float*    bf2 = (float*)(wsb + OFFB_BF2);
    const int stride = gridDim.x * blockDim.x;
    const int i0 = blockIdx.x * blockDim.x + threadIdx.x;

    for (int idx = i0; idx < 16*4*NF1*64; idx += stride) {
        const int lane = idx & 63;
        int q = idx >> 6;
        const int f = q % NF1;  q /= NF1;
        const int tt = q & 3;
        const int w  = q >> 2;
        const int r = lane & 15;
        const int unit = w*16 + tt*4 + (r >> 2);
        const int gate = r & 3;
        const int grow = gate * H1u + unit;
        _Float16* dst = wf1 + (size_t)idx * 8;
        #pragma unroll
        for (int e = 0; e < 8; ++e) {
            const int k = f*32 + (lane >> 4)*8 + e;
            const float v = (k < NF) ? Wih1[grow*NF + k]
                                     : Whh1[grow*H1u + (k - NF)];
            dst[e] = (_Float16)v;
        }
    }
    for (int idx = i0; idx < 16*2*NF2*64; idx += stride) {
        const int lane = idx & 63;
        int q = idx >> 6;
        const int f = q % NF2;  q /= NF2;
        const int tt = q & 1;
        const int w  = q >> 1;
        const int r = lane & 15;
        const int unit = w*8 + tt*4 + (r >> 2);
        const int gate = r & 3;
        const int grow = gate * H2u + unit;
        _Float16* dst = wf2 + (size_t)idx * 8;
        #pragma unroll
        for (int e = 0; e < 8; ++e) {
            const int k = f*32 + (lane >> 4)*8 + e;
            const float v = (k < H1u) ? Wih2[grow*H1u + k]
                                      : Whh2[grow*H2u + (k - H1u)];
            dst[e] = (_Float16)v;
        }
    }
    for (int idx = i0; idx < 16*4*4*4; idx += stride) {
        const int reg = idx & 3, lg = (idx >> 2) & 3;
        const int tt = (idx >> 4) & 3, w = idx >> 6;
        const int unit = w*16 + tt*4 + lg;
        const int grow = reg * H1u + unit;
        bf1[idx] = bih1[grow] + bhh1[grow];
    }
    for (int idx = i0; idx < 16*2*4*4; idx += stride) {
        const int reg = idx & 3, lg = (idx >> 2) & 3;
        const int tt = (idx >> 4) & 1, w = idx >> 5;
        const int unit = w*8 + tt*4 + lg;
        const int grow = reg * H2u + unit;
        bf2[idx] = bih2[grow] + bhh2[grow];
    }
}

__device__ __forceinline__ void load_x_frags(half8* xf, const float* __restrict__ x,
                                             int b0, int b, int g, int t)
{
    #pragma unroll
    for (int f = 0; f < 2; ++f) {
        const float* xp = x + (((size_t)(b0 + b)) * Tt + t) * NF + f * 32 + g * 8;
        const float4 lo = *(const float4*)xp;
        const float4 hi = *(const float4*)(xp + 4);
        half8 v;
        v[0] = (_Float16)lo.x; v[1] = (_Float16)lo.y;
        v[2] = (_Float16)lo.z; v[3] = (_Float16)lo.w;
        v[4] = (_Float16)hi.x; v[5] = (_Float16)hi.y;
        v[6] = (_Float16)hi.z; v[7] = (_Float16)hi.w;
        xf[f] = v;
    }
}

// ---------------- persistent recurrence: same-XCD groups, tagged L2-local exchange ----------------
__global__ __launch_bounds__(NTHR, 1) void lstm_v12(
    const float* __restrict__ x, char* wsb, float* __restrict__ out)
{
    __shared__ char ldsraw[4 * 2048];  // per-wave: h1f 1KB | h2f 512B | l_o 512B
    __shared__ int s_claim;

    const int tid  = threadIdx.x;
    const int w    = tid >> 6;
    const int lane = tid & 63;
    const int g    = lane >> 4;
    const int b    = lane & 15;

    // ---- claim a worker slot on this block's physical XCD ----
    {
        unsigned* clm = (unsigned*)(wsb + OFFB_CLM);
        if (tid == 0) {
            const int xcd = xcc_id();
            const unsigned idx = __hip_atomic_fetch_add(&clm[xcd * 16], 1u,
                                     __ATOMIC_RELAXED, __HIP_MEMORY_SCOPE_AGENT);
            s_claim = (xcd << 8) | (idx < 8u ? (int)idx : 255);
        }
        __syncthreads();
    }
    const int cv = s_claim;
    if ((cv & 255) == 255) return;            // surplus block
    const int idx   = cv & 255;
    const int xcd   = cv >> 8;
    const int grp   = xcd * 2 + (idx >> 2);   // all 4 slices of grp share one XCD/L2
    const int slice = idx & 3;
    const int W     = slice * 4 + w;
    const int b0    = grp * 16;

    const _Float16* wf1g = (const _Float16*)(wsb + OFFB_WF1);
    const _Float16* wf2g = (const _Float16*)(wsb + OFFB_WF2);
    const float*    bf1g = (const float*)(wsb + OFFB_BF1);
    const float*    bf2g = (const float*)(wsb + OFFB_BF2);
    char*           p1   = wsb + OFFB_P1;
    char*           p2   = wsb + OFFB_P2;

    char* myl = ldsraw + w * 2048;
    float* l_h1f = (float*)(myl);            // [b16][uloc16] tagged f32
    float* l_h2f = (float*)(myl + 1024);     // [b16][uloc8]  tagged f32
    float* l_o   = (float*)(myl + 1536);     // [b16][uloc8]  f32

    // ---- one-time: weight fragments + biases -> registers ----
    half8 wA1[NT1][NF1];
    half8 wA2[NT2][NF2];
    #pragma unroll
    for (int tt = 0; tt < NT1; ++tt)
        #pragma unroll
        for (int f = 0; f < NF1; ++f)
            wA1[tt][f] = *(const half8*)(wf1g + ((size_t)(((W*4 + tt)*NF1 + f) * 64 + lane)) * 8);
    #pragma unroll
    for (int tt = 0; tt < NT2; ++tt)
        #pragma unroll
        for (int f = 0; f < NF2; ++f)
            wA2[tt][f] = *(const half8*)(wf2g + ((size_t)(((W*2 + tt)*NF2 + f) * 64 + lane)) * 8);

    f32x4 bias1[NT1], bias2[NT2];
    #pragma unroll
    for (int tt = 0; tt < NT1; ++tt)
        bias1[tt] = *(const f32x4*)(bf1g + ((W*4 + tt)*4 + g) * 4);
    #pragma unroll
    for (int tt = 0; tt < NT2; ++tt)
        bias2[tt] = *(const f32x4*)(bf2g + ((W*2 + tt)*4 + g) * 4);

    float c1s[NT1] = {0.f, 0.f, 0.f, 0.f};
    float c2s[NT2] = {0.f, 0.f};

    half8 hz = {};
    half8 hf[8]  = {hz, hz, hz, hz, hz, hz, hz, hz};
    half8 h2f[4] = {hz, hz, hz, hz};
    half8 xf[2];
    load_x_frags(xf, x, b0, b, g, 0);

    int  strikes = 0;
    bool slow = false;

    for (int t = 0; t <= Tt; ++t) {
        const unsigned tg = (unsigned)(t + 1) & 255u;

        // ================ L1: compute h1(t) -> LDS stage (tagged) ================
        if (t < Tt) {
            f32x4 acc[NT1] = {};
            #pragma unroll
            for (int tt = 0; tt < NT1; ++tt) {
                acc[tt] = __builtin_amdgcn_mfma_f32_16x16x32_f16(wA1[tt][0], xf[0], acc[tt], 0, 0, 0);
                acc[tt] = __builtin_amdgcn_mfma_f32_16x16x32_f16(wA1[tt][1], xf[1], acc[tt], 0, 0, 0);
            }
            #pragma unroll
            for (int f = 0; f < 8; ++f)
                #pragma unroll
                for (int tt = 0; tt < NT1; ++tt)
                    acc[tt] = __builtin_amdgcn_mfma_f32_16x16x32_f16(wA1[tt][2 + f], hf[f], acc[tt], 0, 0, 0);
            #pragma unroll
            for (int tt = 0; tt < NT1; ++tt) {
                const float iv = sigf(acc[tt][0] + bias1[tt][0]);
                const float fv = sigf(acc[tt][1] + bias1[tt][1]);
                const float gv = tanhfast(acc[tt][2] + bias1[tt][2]);
                const float ov = sigf(acc[tt][3] + bias1[tt][3]);
                const float c = fmaf(fv, c1s[tt], iv * gv);
                c1s[tt] = c;
                const float h = ov * tanhfast(c);
                l_h1f[b * 16 + tt * 4 + g] = tagf(h, tg);
            }
        }
        // ================ L2: compute h2(t-1) -> LDS stage (tagged) + out ================
        if (t >= 1) {
            f32x4 acc[NT2] = {};
            #pragma unroll
            for (int f = 0; f < 8; ++f)
                #pragma unroll
                for (int tt = 0; tt < NT2; ++tt)
                    acc[tt] = __builtin_amdgcn_mfma_f32_16x16x32_f16(wA2[tt][f], hf[f], acc[tt], 0, 0, 0);
            #pragma unroll
            for (int f = 0; f < 4; ++f)
                #pragma unroll
                for (int tt = 0; tt < NT2; ++tt)
                    acc[tt] = __builtin_amdgcn_mfma_f32_16x16x32_f16(wA2[tt][8 + f], h2f[f], acc[tt], 0, 0, 0);
            #pragma unroll
            for (int tt = 0; tt < NT2; ++tt) {
                const float iv = sigf(acc[tt][0] + bias2[tt][0]);
                const float fv = sigf(acc[tt][1] + bias2[tt][1]);
                const float gv = tanhfast(acc[tt][2] + bias2[tt][2]);
                const float ov = sigf(acc[tt][3] + bias2[tt][3]);
                const float c = fmaf(fv, c2s[tt], iv * gv);
                c2s[tt] = c;
                const float h = ov * tanhfast(c);
                if (t < Tt) l_h2f[b * 8 + tt * 4 + g] = tagf(h, tg);
                l_o[b * 8 + tt * 4 + g] = h;
            }
        }
        LGKM_BAR();   // pin LDS stage writes before type-punned readbacks

        // ================ producer: coalesced PLAIN stores (local-L2 write-back) ================
        if (t < Tt) {
            {   // h1: one dwordx4 per lane (wave slab contiguous 1KB)
                const float4 v = ((const float4_a*)l_h1f)[lane];
                *(float4_a*)(p1 + (size_t)((t & 1) * 16 + grp) * 16384 + W * 1024 + lane * 16) = v;
            }
            {   // h2: one dwordx2 per lane (wave slab contiguous 512B)
                ull v2;
                if (t >= 1) v2 = ((const ull_a*)l_h2f)[lane];
                else {
                    const unsigned z = __float_as_uint(tagf(0.f, 1u));
                    v2 = (ull)z | ((ull)z << 32);
                }
                *(ull_a*)(p2 + (size_t)(((t + 1) & 1) * 16 + grp) * 8192 + W * 512 + lane * 8) = v2;
            }
        }
        // ================ out writes + x prefetch (overlap store propagation) ================
        if (t >= 1 && lane < 32) {
            const int s_ = t - 1;
            const int bb = lane >> 1, q = lane & 1;
            const float4 ov = *(const float4_a*)(l_o + bb * 8 + q * 4);
            *(float4*)&out[((size_t)(b0 + bb) * Tt + s_) * H2u + W * 8 + q * 4] = ov;
            if (s_ == Tt - 1)
                *(float4*)&out[(size_t)Bb * Tt * H2u + (size_t)(b0 + bb) * H2u + W * 8 + q * 4] = ov;
        }
        if (t + 1 < Tt) load_x_frags(xf, x, b0, b, g, t + 1);

        // ================ consumer: tagged sc0 retry loads (L2-local), agent fallback ================
        if (t < Tt) {
            const char* p1r = p1 + (size_t)((t & 1) * 16 + grp) * 16384;
            const char* p2r = p2 + (size_t)(((t + 1) & 1) * 16 + grp) * 8192;
            const char* pb  = p1r + (g >> 1) * 1024 + b * 64 + (g & 1) * 32;  // h1 frag bases
            const char* pc  = p2r + g * 512 + b * 32;                         // h2 frag bases

            bool got = false;
            if (!slow) {
                int att = 0;
                for (;;) {
                    unsigned bad = 0;
                    i32x4 o0, o1, o2, o3, o4, o5, o6, o7;
                    LOAD8_SC0(pb, pb + 4096, o0, o1, o2, o3, o4, o5, o6, o7);
                    bad |= chki(o0,tg)|chki(o1,tg)|chki(o2,tg)|chki(o3,tg)
                         | chki(o4,tg)|chki(o5,tg)|chki(o6,tg)|chki(o7,tg);
                    hf[0] = mk8i(o0, o1); hf[1] = mk8i(o2, o3);
                    hf[2] = mk8i(o4, o5); hf[3] = mk8i(o6, o7);
                    LOAD8_SC0(pb + 8192, pb + 12288, o0, o1, o2, o3, o4, o5, o6, o7);
                    bad |= chki(o0,tg)|chki(o1,tg)|chki(o2,tg)|chki(o3,tg)
                         | chki(o4,tg)|chki(o5,tg)|chki(o6,tg)|chki(o7,tg);
                    hf[4] = mk8i(o0, o1); hf[5] = mk8i(o2, o3);
                    hf[6] = mk8i(o4, o5); hf[7] = mk8i(o6, o7);
                    LOAD8_SC0(pc, pc + 4096, o0, o1, o2, o3, o4, o5, o6, o7);
                    bad |= chki(o0,tg)|chki(o1,tg)|chki(o2,tg)|chki(o3,tg)
                         | chki(o4,tg)|chki(o5,tg)|chki(o6,tg)|chki(o7,tg);
                    h2f[0] = mk8i(o0, o1); h2f[1] = mk8i(o2, o3);
                    h2f[2] = mk8i(o4, o5); h2f[3] = mk8i(o6, o7);
                    if (__all((int)(bad == 0u))) { got = true; break; }
                    if (++att >= 64) { if (++strikes >= 4) slow = true; break; }
                    __builtin_amdgcn_s_sleep(1);
                }
            }
            if (!got) {
                // proven-progress agent-scope fallback (rare / latched-slow path)
                for (;;) {
                    unsigned bad = 0;
                    #pragma unroll
                    for (int f = 0; f < 8; ++f) {
                        const ull* a = (const ull*)(p1r + (2*f + (g >> 1)) * 1024 + b * 64 + (g & 1) * 32);
                        const ull a0 = __hip_atomic_load(a + 0, __ATOMIC_RELAXED, __HIP_MEMORY_SCOPE_AGENT);
                        const ull a1 = __hip_atomic_load(a + 1, __ATOMIC_RELAXED, __HIP_MEMORY_SCOPE_AGENT);
                        const ull a2 = __hip_atomic_load(a + 2, __ATOMIC_RELAXED, __HIP_MEMORY_SCOPE_AGENT);
                        const ull a3 = __hip_atomic_load(a + 3, __ATOMIC_RELAXED, __HIP_MEMORY_SCOPE_AGENT);
                        bad |= chku(a0,tg)|chku(a1,tg)|chku(a2,tg)|chku(a3,tg);
                        hf[f] = mk8u(a0, a1, a2, a3);
                    }
                    #pragma unroll
                    for (int f = 0; f < 4; ++f) {
                        const ull* a = (const ull*)(p2r + (4*f + g) * 512 + b * 32);
                        const ull a0 = __hip_atomic_load(a + 0, __ATOMIC_RELAXED, __HIP_MEMORY_SCOPE_AGENT);
                        const ull a1 = __hip_atomic_load(a + 1, __ATOMIC_RELAXED, __HIP_MEMORY_SCOPE_AGENT);
                        const ull a2 = __hip_atomic_load(a + 2, __ATOMIC_RELAXED, __HIP_MEMORY_SCOPE_AGENT);
                        const ull a3 = __hip_atomic_load(a + 3, __ATOMIC_RELAXED, __HIP_MEMORY_SCOPE_AGENT);
                        bad |= chku(a0,tg)|chku(a1,tg)|chku(a2,tg)|chku(a3,tg);
                        h2f[f] = mk8u(a0, a1, a2, a3);
                    }
                    if (__all((int)(bad == 0u))) break;
                    __builtin_amdgcn_s_sleep(1);
                    asm volatile("" ::: "memory");
                }
            }
        }
    }
}

extern "C" void kernel_launch(void* const* d_in, const int* in_sizes, int n_in,
                              void* d_out, int out_size, void* d_ws, size_t ws_size,
                              hipStream_t stream) {
    const float* x    = (const float*)d_in[0];
    const float* Wih1 = (const float*)d_in[1];
    const float* Whh1 = (const float*)d_in[2];
    const float* bih1 = (const float*)d_in[3];
    const float* bhh1 = (const float*)d_in[4];
    const float* Wih2 = (const float*)d_in[5];
    const float* Whh2 = (const float*)d_in[6];
    const float* bih2 = (const float*)d_in[7];
    const float* bhh2 = (const float*)d_in[8];
    char*  wsb = (char*)d_ws;
    float* out = (float*)d_out;

    prep4<<<256, 256, 0, stream>>>(Wih1, Whh1, bih1, bhh1,
                                   Wih2, Whh2, bih2, bhh2, wsb);
    // zero panels (kills cross-launch tag aliasing) + claim counters, every launch
    hipMemsetAsync((void*)(wsb + OFFB_P1), 0, SZB_P1 + SZB_P2 + SZB_CLM, stream);
    lstm_v12<<<NLAUNCH, NTHR, 0, stream>>>(x, wsb, out);
}